// Round 3
// baseline (905.935 us; speedup 1.0000x reference)
//
#include <hip/hip_runtime.h>
#include <hip/hip_bf16.h>

#define D_HID 32
#define D_IN 128
#define NEG 0.2f

typedef unsigned short u16;

__device__ __forceinline__ float b2f(u16 u){
  union { unsigned int i; float f; } c; c.i = ((unsigned int)u) << 16; return c.f;
}

// dtype-agnostic float load: f32 ? fp32[i] : bf16[i]
__device__ __forceinline__ float ldf(const void* __restrict__ p, int f32, long long i){
  return f32 ? ((const float*)p)[i] : b2f(((const u16*)p)[i]);
}

__device__ __forceinline__ void atomAddF(float* p, float v){
  (void)__hip_atomic_fetch_add(p, v, __ATOMIC_RELAXED, __HIP_MEMORY_SCOPE_AGENT);
}

// flags[0]: edge_index is int64-layout (high dwords of first 64 entries all zero).
// flags[1]: float inputs are fp32 (u16-word exponent sanity test).
__global__ void detect_flags(const int* __restrict__ ei, const u16* __restrict__ xw,
                             int* __restrict__ flags){
  if (blockIdx.x == 0 && threadIdx.x == 0){
    int allzero = 1;
    for (int i = 0; i < 64; ++i){
      if (ei[2*i+1] != 0){ allzero = 0; break; }
    }
    flags[0] = allzero;
    int insane = 0;
    for (int i = 0; i < 256; ++i){
      int e = (xw[i] >> 7) & 0xFF;
      if (e < 100 || e > 140) insane++;
    }
    flags[1] = (insane > 16) ? 1 : 0;
  }
}

__device__ __forceinline__ void edge_nodes(const int* __restrict__ ei, int E_, int is64,
                                           int e, int& src, int& dst){
  if (is64){ src = ei[2*e]; dst = ei[2*E_ + 2*e]; }
  else     { src = ei[e];   dst = ei[E_ + e]; }
}

// x: [N,128], W: [128,32] -> xl, xr: [N,32] fp32
__global__ void node_gemm1(const void* __restrict__ x,
                           const void* __restrict__ Wl,
                           const void* __restrict__ Wr,
                           const int* __restrict__ flags,
                           float* __restrict__ xl, float* __restrict__ xr, int N_)
{
  int t = blockIdx.x * blockDim.x + threadIdx.x;
  int n = t >> 5, k = t & 31;
  if (n >= N_) return;
  int f32 = flags[1];
  long long xb = (long long)n * D_IN;
  float sl = 0.f, sr = 0.f;
  #pragma unroll 8
  for (int i = 0; i < D_IN; ++i){
    float xv = ldf(x, f32, xb + i);
    sl = fmaf(xv, ldf(Wl, f32, i*D_HID + k), sl);
    sr = fmaf(xv, ldf(Wr, f32, i*D_HID + k), sr);
  }
  xl[(size_t)n*D_HID + k] = sl;
  xr[(size_t)n*D_HID + k] = sr;
}

// h: [N,32] fp32 (ours), W: [32,32] -> hl, hr: [N,32] fp32
__global__ void node_gemm2(const float* __restrict__ h,
                           const void* __restrict__ Wl,
                           const void* __restrict__ Wr,
                           const int* __restrict__ flags,
                           float* __restrict__ hl, float* __restrict__ hr, int N_)
{
  int t = blockIdx.x * blockDim.x + threadIdx.x;
  int n = t >> 5, k = t & 31;
  if (n >= N_) return;
  int f32 = flags[1];
  const float* hrow = h + (size_t)n * D_HID;
  float sl = 0.f, sr = 0.f;
  #pragma unroll
  for (int i = 0; i < D_HID; ++i){
    float xv = hrow[i];
    sl = fmaf(xv, ldf(Wl, f32, i*D_HID + k), sl);
    sr = fmaf(xv, ldf(Wr, f32, i*D_HID + k), sr);
  }
  hl[(size_t)n*D_HID + k] = sl;
  hr[(size_t)n*D_HID + k] = sr;
}

// per edge: logit = att . leaky(xl[src]+xr[dst]); ex = exp(logit); s[dst] += ex
__global__ void edge_logit(const int* __restrict__ ei, const int* __restrict__ flags,
                           const float* __restrict__ xl, const float* __restrict__ xr,
                           const void* __restrict__ att,
                           float* __restrict__ ex, float* __restrict__ s, int E_)
{
  int e = blockIdx.x * blockDim.x + threadIdx.x;
  if (e >= E_) return;
  int is64 = flags[0], f32 = flags[1];
  int src, dst;
  edge_nodes(ei, E_, is64, e, src, dst);
  const float4* a = (const float4*)(xl + (size_t)src * D_HID);
  const float4* b = (const float4*)(xr + (size_t)dst * D_HID);
  float logit = 0.f;
  #pragma unroll
  for (int q = 0; q < 8; ++q){
    float4 av = a[q], bv = b[q];
    float h0 = av.x + bv.x; h0 = h0 > 0.f ? h0 : NEG*h0;
    float h1 = av.y + bv.y; h1 = h1 > 0.f ? h1 : NEG*h1;
    float h2 = av.z + bv.z; h2 = h2 > 0.f ? h2 : NEG*h2;
    float h3 = av.w + bv.w; h3 = h3 > 0.f ? h3 : NEG*h3;
    logit = fmaf(h0, ldf(att, f32, q*4+0), logit);
    logit = fmaf(h1, ldf(att, f32, q*4+1), logit);
    logit = fmaf(h2, ldf(att, f32, q*4+2), logit);
    logit = fmaf(h3, ldf(att, f32, q*4+3), logit);
  }
  // real logits are |.| <~ 10; clamp keeps diagnostics finite if an assumption breaks
  logit = fminf(logit, 60.f);
  float ev = expf(logit);
  ex[e] = ev;
  atomAddF(&s[dst], ev);
}

// per (edge, k): agg[dst][k] += (ex[e]/(s[dst]+1e-16)) * xl[src][k]
__global__ void edge_aggr(const int* __restrict__ ei, const int* __restrict__ flags,
                          const float* __restrict__ xl, const float* __restrict__ ex,
                          const float* __restrict__ s, float* __restrict__ agg, int E_)
{
  long long t = (long long)blockIdx.x * blockDim.x + threadIdx.x;
  int e = (int)(t >> 5);
  int k = (int)(t & 31);
  if (e >= E_) return;
  int is64 = flags[0];
  int src, dst;
  edge_nodes(ei, E_, is64, e, src, dst);
  float alpha = ex[e] / (s[dst] + 1e-16f);
  float v = alpha * xl[(size_t)src*D_HID + k];
  atomAddF(&agg[(size_t)dst*D_HID + k], v);
}

// in-place: agg = relu(agg + b)
__global__ void bias_relu(float* __restrict__ agg, const void* __restrict__ b,
                          const int* __restrict__ flags, int total){
  int t = blockIdx.x * blockDim.x + threadIdx.x;
  if (t >= total) return;
  float v = agg[t] + ldf(b, flags[1], t & 31);
  agg[t] = v > 0.f ? v : 0.f;
}

// out = fp32(agg + b)  -- reference output dtype is float32
__global__ void bias_out(const float* __restrict__ agg, const void* __restrict__ b,
                         const int* __restrict__ flags,
                         float* __restrict__ out, int total){
  int t = blockIdx.x * blockDim.x + threadIdx.x;
  if (t >= total) return;
  float v = agg[t] + ldf(b, flags[1], t & 31);
  out[t] = v;
}

extern "C" void kernel_launch(void* const* d_in, const int* in_sizes, int n_in,
                              void* d_out, int out_size, void* d_ws, size_t ws_size,
                              hipStream_t stream)
{
  const void* x   = d_in[0];
  const int*  ei  = (const int*)d_in[1];
  const void* W1l = d_in[2];
  const void* W1r = d_in[3];
  const void* att1= d_in[4];
  const void* b1  = d_in[5];
  const void* W2l = d_in[6];
  const void* W2r = d_in[7];
  const void* att2= d_in[8];
  const void* b2  = d_in[9];
  float* out = (float*)d_out;

  int N_ = in_sizes[0] / D_IN;
  int E_ = in_sizes[1] / 2;

  char* ws = (char*)d_ws;
  size_t off = 0;
  auto carve = [&](size_t bytes) -> char* {
    char* p = ws + off;
    off += (bytes + 255) & ~(size_t)255;
    return p;
  };
  float* xl   = (float*)carve((size_t)N_ * D_HID * 4);
  float* xr   = (float*)carve((size_t)N_ * D_HID * 4);
  float* ex   = (float*)carve((size_t)E_ * 4);
  float* s    = (float*)carve((size_t)N_ * 4);
  float* agg  = (float*)carve((size_t)N_ * D_HID * 4);
  int*   flags= (int*)carve(256);

  const int tpb = 256;
  int gNK = (N_ * D_HID + tpb - 1) / tpb;
  int gE  = (E_ + tpb - 1) / tpb;
  long long ethreads = (long long)E_ * D_HID;
  int gEK = (int)((ethreads + tpb - 1) / tpb);

  detect_flags<<<1, 64, 0, stream>>>(ei, (const u16*)x, flags);

  // ---- layer 1 ----
  hipMemsetAsync(s, 0, (size_t)N_ * 4, stream);
  hipMemsetAsync(agg, 0, (size_t)N_ * D_HID * 4, stream);
  node_gemm1<<<gNK, tpb, 0, stream>>>(x, W1l, W1r, flags, xl, xr, N_);
  edge_logit<<<gE, tpb, 0, stream>>>(ei, flags, xl, xr, att1, ex, s, E_);
  edge_aggr<<<gEK, tpb, 0, stream>>>(ei, flags, xl, ex, s, agg, E_);
  bias_relu<<<gNK, tpb, 0, stream>>>(agg, b1, flags, N_ * D_HID);

  // ---- layer 2 ----
  node_gemm2<<<gNK, tpb, 0, stream>>>(agg, W2l, W2r, flags, xl, xr, N_);
  hipMemsetAsync(s, 0, (size_t)N_ * 4, stream);
  hipMemsetAsync(agg, 0, (size_t)N_ * D_HID * 4, stream);
  edge_logit<<<gE, tpb, 0, stream>>>(ei, flags, xl, xr, att2, ex, s, E_);
  edge_aggr<<<gEK, tpb, 0, stream>>>(ei, flags, xl, ex, s, agg, E_);
  bias_out<<<gNK, tpb, 0, stream>>>(agg, b2, flags, out, N_ * D_HID);
}

// Round 4
// 730.943 us; speedup vs baseline: 1.2394x; 1.2394x over previous
//
#include <hip/hip_runtime.h>
#include <hip/hip_bf16.h>

#define D_HID 32
#define D_IN 128
#define NEG 0.2f

typedef unsigned short u16;

__device__ __forceinline__ float b2f(u16 u){
  union { unsigned int i; float f; } c; c.i = ((unsigned int)u) << 16; return c.f;
}

// dtype-agnostic float load: f32 ? fp32[i] : bf16[i]
__device__ __forceinline__ float ldf(const void* __restrict__ p, int f32, long long i){
  return f32 ? ((const float*)p)[i] : b2f(((const u16*)p)[i]);
}

__device__ __forceinline__ int atomAddI(int* p, int v){
  return __hip_atomic_fetch_add(p, v, __ATOMIC_RELAXED, __HIP_MEMORY_SCOPE_AGENT);
}

// flags[0]: edge_index is int64-layout. flags[1]: float inputs are fp32.
__global__ void detect_flags(const int* __restrict__ ei, const u16* __restrict__ xw,
                             int* __restrict__ flags){
  if (blockIdx.x == 0 && threadIdx.x == 0){
    int allzero = 1;
    for (int i = 0; i < 64; ++i){
      if (ei[2*i+1] != 0){ allzero = 0; break; }
    }
    flags[0] = allzero;
    int insane = 0;
    for (int i = 0; i < 256; ++i){
      int e = (xw[i] >> 7) & 0xFF;
      if (e < 100 || e > 140) insane++;
    }
    flags[1] = (insane > 16) ? 1 : 0;
  }
}

__device__ __forceinline__ void edge_nodes(const int* __restrict__ ei, int E_, int is64,
                                           int e, int& src, int& dst){
  if (is64){ src = ei[2*e]; dst = ei[2*E_ + 2*e]; }
  else     { src = ei[e];   dst = ei[E_ + e]; }
}

// ---------------- node transforms ----------------
// x: [N,128], W: [128,32] -> xl, xr: [N,32] fp32
__global__ void node_gemm1(const void* __restrict__ x,
                           const void* __restrict__ Wl,
                           const void* __restrict__ Wr,
                           const int* __restrict__ flags,
                           float* __restrict__ xl, float* __restrict__ xr, int N_)
{
  int t = blockIdx.x * blockDim.x + threadIdx.x;
  int n = t >> 5, k = t & 31;
  if (n >= N_) return;
  int f32 = flags[1];
  long long xb = (long long)n * D_IN;
  float sl = 0.f, sr = 0.f;
  #pragma unroll 8
  for (int i = 0; i < D_IN; ++i){
    float xv = ldf(x, f32, xb + i);
    sl = fmaf(xv, ldf(Wl, f32, i*D_HID + k), sl);
    sr = fmaf(xv, ldf(Wr, f32, i*D_HID + k), sr);
  }
  xl[(size_t)n*D_HID + k] = sl;
  xr[(size_t)n*D_HID + k] = sr;
}

// h: [N,32] fp32, W: [32,32] -> hl, hr: [N,32] fp32
__global__ void node_gemm2(const float* __restrict__ h,
                           const void* __restrict__ Wl,
                           const void* __restrict__ Wr,
                           const int* __restrict__ flags,
                           float* __restrict__ hl, float* __restrict__ hr, int N_)
{
  int t = blockIdx.x * blockDim.x + threadIdx.x;
  int n = t >> 5, k = t & 31;
  if (n >= N_) return;
  int f32 = flags[1];
  const float* hrow = h + (size_t)n * D_HID;
  float sl = 0.f, sr = 0.f;
  #pragma unroll
  for (int i = 0; i < D_HID; ++i){
    float xv = hrow[i];
    sl = fmaf(xv, ldf(Wl, f32, i*D_HID + k), sl);
    sr = fmaf(xv, ldf(Wr, f32, i*D_HID + k), sr);
  }
  hl[(size_t)n*D_HID + k] = sl;
  hr[(size_t)n*D_HID + k] = sr;
}

// ---------------- CSR build ----------------
__global__ void count_deg(const int* __restrict__ ei, const int* __restrict__ flags,
                          int* __restrict__ deg, int E_){
  int e = blockIdx.x * blockDim.x + threadIdx.x;
  if (e >= E_) return;
  int is64 = flags[0];
  int dst = is64 ? ei[2*E_ + 2*e] : ei[E_ + e];
  (void)atomAddI(&deg[dst], 1);
}

__global__ void scan_partial(const int* __restrict__ deg, int* __restrict__ bsum, int N_){
  __shared__ int sd[256];
  int g = blockIdx.x*256 + threadIdx.x;
  sd[threadIdx.x] = (g < N_) ? deg[g] : 0;
  __syncthreads();
  for (int off = 128; off > 0; off >>= 1){
    if (threadIdx.x < off) sd[threadIdx.x] += sd[threadIdx.x + off];
    __syncthreads();
  }
  if (threadIdx.x == 0) bsum[blockIdx.x] = sd[0];
}

__global__ void scan_bsum(int* __restrict__ bsum, int NB){
  if (blockIdx.x == 0 && threadIdx.x == 0){
    int run = 0;
    for (int i = 0; i < NB; ++i){ int t = bsum[i]; bsum[i] = run; run += t; }
  }
}

// NOTE: deg_in and cursor may alias (read-before-write within own chunk only).
__global__ void scan_write(const int* deg_in, const int* __restrict__ bsum,
                           int* __restrict__ row, int* cursor, int N_, int E_){
  __shared__ int sd[256];
  int t = threadIdx.x, g = blockIdx.x*256 + t;
  int v = (g < N_) ? deg_in[g] : 0;
  sd[t] = v;
  __syncthreads();
  for (int off = 1; off < 256; off <<= 1){
    int tmp = (t >= off) ? sd[t-off] : 0;
    __syncthreads();
    sd[t] += tmp;
    __syncthreads();
  }
  int excl = sd[t] - v;
  int base = bsum[blockIdx.x];
  if (g < N_){ row[g] = base + excl; cursor[g] = base + excl; }
  if (g == 0) row[N_] = E_;
}

__global__ void scatter_edges(const int* __restrict__ ei, const int* __restrict__ flags,
                              int* __restrict__ cursor, int* __restrict__ csr_src, int E_){
  int e = blockIdx.x * blockDim.x + threadIdx.x;
  if (e >= E_) return;
  int is64 = flags[0];
  int src, dst;
  edge_nodes(ei, E_, is64, e, src, dst);
  int pos = atomAddI(&cursor[dst], 1);
  csr_src[pos] = src;
}

// ---------------- fused per-dst gather: softmax + weighted sum + bias ----------------
// one wave per dst node; 2 edges in flight (half-wave each); lane k of 32 owns feature k
__global__ void gat_gather(const int* __restrict__ row, const int* __restrict__ csr_src,
                           const float* __restrict__ xl, const float* __restrict__ xr,
                           const void* __restrict__ att, const void* __restrict__ bias,
                           const int* __restrict__ flags,
                           float* __restrict__ outp, int N_, int do_relu)
{
  int n = blockIdx.x * (blockDim.x >> 6) + (threadIdx.x >> 6);
  if (n >= N_) return;
  int lane = threadIdx.x & 63;
  int half = lane >> 5, k = lane & 31;
  int f32 = flags[1];
  float attk = ldf(att, f32, k);
  float xrk = xr[(size_t)n*D_HID + k];
  int rs = row[n], re = row[n+1];
  float acc = 0.f, ssum = 0.f;
  for (int i = rs + half; i < re; i += 2){
    int src = csr_src[i];
    float xlv = xl[(size_t)src*D_HID + k];
    float h = xlv + xrk;
    h = h > 0.f ? h : NEG*h;
    float p = h * attk;
    p += __shfl_xor(p, 16, 32);
    p += __shfl_xor(p,  8, 32);
    p += __shfl_xor(p,  4, 32);
    p += __shfl_xor(p,  2, 32);
    p += __shfl_xor(p,  1, 32);
    p = fminf(p, 60.f);          // safety clamp; real logits |.| <~ 15
    float ev = __expf(p);
    ssum += ev;
    acc = fmaf(ev, xlv, acc);
  }
  // combine the two half-wave partial sums (lane^32 has same k)
  acc  += __shfl_xor(acc, 32, 64);
  ssum += __shfl_xor(ssum, 32, 64);
  if (half == 0){
    float v = acc / (ssum + 1e-16f) + ldf(bias, f32, k);
    if (do_relu) v = v > 0.f ? v : 0.f;
    outp[(size_t)n*D_HID + k] = v;
  }
}

extern "C" void kernel_launch(void* const* d_in, const int* in_sizes, int n_in,
                              void* d_out, int out_size, void* d_ws, size_t ws_size,
                              hipStream_t stream)
{
  const void* x   = d_in[0];
  const int*  ei  = (const int*)d_in[1];
  const void* W1l = d_in[2];
  const void* W1r = d_in[3];
  const void* att1= d_in[4];
  const void* b1  = d_in[5];
  const void* W2l = d_in[6];
  const void* W2r = d_in[7];
  const void* att2= d_in[8];
  const void* b2  = d_in[9];
  float* out = (float*)d_out;

  int N_ = in_sizes[0] / D_IN;
  int E_ = in_sizes[1] / 2;

  char* ws = (char*)d_ws;
  size_t off = 0;
  auto carve = [&](size_t bytes) -> char* {
    char* p = ws + off;
    off += (bytes + 255) & ~(size_t)255;
    return p;
  };
  float* xl     = (float*)carve((size_t)N_ * D_HID * 4);
  float* xr     = (float*)carve((size_t)N_ * D_HID * 4);
  float* h      = (float*)carve((size_t)N_ * D_HID * 4);
  int*   csr_src= (int*)  carve((size_t)E_ * 4);
  int*   row    = (int*)  carve((size_t)(N_ + 1) * 4);
  int*   deg    = (int*)  carve((size_t)N_ * 4);   // doubles as cursor after scan
  int*   bsum   = (int*)  carve(4096);
  int*   flags  = (int*)  carve(256);
  int*   cursor = deg;

  const int tpb = 256;
  int gNK = (N_ * D_HID + tpb - 1) / tpb;   // node*feature grid
  int gE  = (E_ + tpb - 1) / tpb;           // edge grid
  int NB  = (N_ + 255) / 256;               // scan chunks
  int gW  = (N_ + 3) / 4;                   // wave-per-node grid (4 waves/block)

  detect_flags<<<1, 64, 0, stream>>>(ei, (const u16*)x, flags);

  // ---- CSR build (shared by both layers) ----
  hipMemsetAsync(deg, 0, (size_t)N_ * 4, stream);
  count_deg<<<gE, tpb, 0, stream>>>(ei, flags, deg, E_);
  scan_partial<<<NB, 256, 0, stream>>>(deg, bsum, N_);
  scan_bsum<<<1, 64, 0, stream>>>(bsum, NB);
  scan_write<<<NB, 256, 0, stream>>>(deg, bsum, row, cursor, N_, E_);
  scatter_edges<<<gE, tpb, 0, stream>>>(ei, flags, cursor, csr_src, E_);

  // ---- layer 1 ----
  node_gemm1<<<gNK, tpb, 0, stream>>>(x, W1l, W1r, flags, xl, xr, N_);
  gat_gather<<<gW, tpb, 0, stream>>>(row, csr_src, xl, xr, att1, b1, flags, h, N_, 1);

  // ---- layer 2 ----
  node_gemm2<<<gNK, tpb, 0, stream>>>(h, W2l, W2r, flags, xl, xr, N_);
  gat_gather<<<gW, tpb, 0, stream>>>(row, csr_src, xl, xr, att2, b2, flags, out, N_, 0);
}

// Round 7
// 580.867 us; speedup vs baseline: 1.5596x; 1.2584x over previous
//
#include <hip/hip_runtime.h>
#include <hip/hip_bf16.h>

#define D_HID 32
#define D_IN 128
#define NEG 0.2f

typedef unsigned short u16;

__device__ __forceinline__ float b2f(u16 u){
  union { unsigned int i; float f; } c; c.i = ((unsigned int)u) << 16; return c.f;
}

// dtype-agnostic float load: f32 ? fp32[i] : bf16[i]
__device__ __forceinline__ float ldf(const void* __restrict__ p, int f32, long long i){
  return f32 ? ((const float*)p)[i] : b2f(((const u16*)p)[i]);
}

__device__ __forceinline__ int atomAddI(int* p, int v){
  return __hip_atomic_fetch_add(p, v, __ATOMIC_RELAXED, __HIP_MEMORY_SCOPE_AGENT);
}

// flags[0]: edge_index is int64-layout (high dwords of first 64 entries all zero).
// flags[1]: float inputs are fp32 (u16-word exponent sanity over 256 words).
__global__ void detect_flags(const int* __restrict__ ei, const u16* __restrict__ xw,
                             int* __restrict__ flags){
  __shared__ int insane_s, nz_s;
  int t = threadIdx.x;                      // 256 threads
  if (t == 0){ insane_s = 0; nz_s = 0; }
  __syncthreads();
  int pred = (t < 64) ? (ei[2*t+1] != 0) : 0;
  int e = (xw[t] >> 7) & 0xFF;
  int bad = (e < 100 || e > 140) ? 1 : 0;
  #pragma unroll
  for (int off = 32; off >= 1; off >>= 1){
    bad  += __shfl_down(bad,  off, 64);
    pred += __shfl_down(pred, off, 64);
  }
  if ((t & 63) == 0){
    atomicAdd(&insane_s, bad);
    atomicAdd(&nz_s, pred);
  }
  __syncthreads();
  if (t == 0){
    flags[0] = (nz_s == 0) ? 1 : 0;
    flags[1] = (insane_s > 16) ? 1 : 0;
  }
}

__device__ __forceinline__ void edge_nodes(const int* __restrict__ ei, int E_, int is64,
                                           int e, int& src, int& dst){
  if (is64){ src = ei[2*e]; dst = ei[2*E_ + 2*e]; }
  else     { src = ei[e];   dst = ei[E_ + e]; }
}

// ---------------- node transform (fp32-exact) ----------------
// One thread per node, all 64 output cols in registers. x row via float4 (read
// once); W via wave-uniform indices -> compiler emits scalar s_load (K$-served,
// parallel to the VALU fma stream). Same fmaf k-order as the r4 kernel ->
// bit-identical results.
template<int K>
__global__ void node_gemm(const void* __restrict__ X,
                          const void* __restrict__ Wl,
                          const void* __restrict__ Wr,
                          const int* __restrict__ flags, int force_f32,
                          float* __restrict__ xl, float* __restrict__ xr, int N_)
{
  int n = blockIdx.x * blockDim.x + threadIdx.x;
  if (n >= N_) return;
  int f32 = force_f32 | flags[1];
  float accl[32], accr[32];
  #pragma unroll
  for (int c = 0; c < 32; ++c){ accl[c] = 0.f; accr[c] = 0.f; }

  if (f32){
    const float* xrow = (const float*)X + (size_t)n * K;
    const float* wl = (const float*)Wl;
    const float* wr = (const float*)Wr;
    for (int k0 = 0; k0 < K; k0 += 4){
      float4 xv = *(const float4*)(xrow + k0);
      #pragma unroll
      for (int kk = 0; kk < 4; ++kk){
        float xs = kk==0 ? xv.x : kk==1 ? xv.y : kk==2 ? xv.z : xv.w;
        int k = k0 + kk;
        #pragma unroll
        for (int c = 0; c < 32; c += 4){
          float4 wl4 = *(const float4*)(wl + k*D_HID + c);
          float4 wr4 = *(const float4*)(wr + k*D_HID + c);
          accl[c+0] = fmaf(xs, wl4.x, accl[c+0]);
          accl[c+1] = fmaf(xs, wl4.y, accl[c+1]);
          accl[c+2] = fmaf(xs, wl4.z, accl[c+2]);
          accl[c+3] = fmaf(xs, wl4.w, accl[c+3]);
          accr[c+0] = fmaf(xs, wr4.x, accr[c+0]);
          accr[c+1] = fmaf(xs, wr4.y, accr[c+1]);
          accr[c+2] = fmaf(xs, wr4.z, accr[c+2]);
          accr[c+3] = fmaf(xs, wr4.w, accr[c+3]);
        }
      }
    }
  } else {
    // generic bf16 fallback (insurance; not expected on this dataset)
    for (int k = 0; k < K; ++k){
      float xs = ldf(X, 0, (long long)n*K + k);
      #pragma unroll
      for (int c = 0; c < 32; ++c){
        accl[c] = fmaf(xs, ldf(Wl, 0, k*D_HID + c), accl[c]);
        accr[c] = fmaf(xs, ldf(Wr, 0, k*D_HID + c), accr[c]);
      }
    }
  }

  float* lo = xl + (size_t)n * D_HID;
  float* ro = xr + (size_t)n * D_HID;
  #pragma unroll
  for (int c = 0; c < 32; c += 4){
    *(float4*)(lo + c) = make_float4(accl[c], accl[c+1], accl[c+2], accl[c+3]);
    *(float4*)(ro + c) = make_float4(accr[c], accr[c+1], accr[c+2], accr[c+3]);
  }
}

// ---------------- CSR build ----------------
__global__ void count_deg(const int* __restrict__ ei, const int* __restrict__ flags,
                          int* __restrict__ deg, int E_){
  int e = blockIdx.x * blockDim.x + threadIdx.x;
  if (e >= E_) return;
  int is64 = flags[0];
  int dst = is64 ? ei[2*E_ + 2*e] : ei[E_ + e];
  (void)atomAddI(&deg[dst], 1);
}

__global__ void scan_partial(const int* __restrict__ deg, int* __restrict__ bsum, int N_){
  __shared__ int sd[256];
  int g = blockIdx.x*256 + threadIdx.x;
  sd[threadIdx.x] = (g < N_) ? deg[g] : 0;
  __syncthreads();
  for (int off = 128; off > 0; off >>= 1){
    if (threadIdx.x < off) sd[threadIdx.x] += sd[threadIdx.x + off];
    __syncthreads();
  }
  if (threadIdx.x == 0) bsum[blockIdx.x] = sd[0];
}

// parallel single-block exclusive scan over NB (<=512) block sums
__global__ void scan_bsum(int* __restrict__ bsum, int NB){
  __shared__ int sd[512];
  int t = threadIdx.x;
  int v = (t < NB) ? bsum[t] : 0;
  sd[t] = v;
  __syncthreads();
  for (int off = 1; off < 512; off <<= 1){
    int tmp = (t >= off) ? sd[t-off] : 0;
    __syncthreads();
    sd[t] += tmp;
    __syncthreads();
  }
  if (t < NB) bsum[t] = sd[t] - v;   // exclusive prefix
}

// NOTE: deg_in and cursor may alias (read-before-write within own chunk only).
__global__ void scan_write(const int* deg_in, const int* __restrict__ bsum,
                           int* __restrict__ row, int* cursor, int N_, int E_){
  __shared__ int sd[256];
  int t = threadIdx.x, g = blockIdx.x*256 + t;
  int v = (g < N_) ? deg_in[g] : 0;
  sd[t] = v;
  __syncthreads();
  for (int off = 1; off < 256; off <<= 1){
    int tmp = (t >= off) ? sd[t-off] : 0;
    __syncthreads();
    sd[t] += tmp;
    __syncthreads();
  }
  int excl = sd[t] - v;
  int base = bsum[blockIdx.x];
  if (g < N_){ row[g] = base + excl; cursor[g] = base + excl; }
  if (g == 0) row[N_] = E_;
}

__global__ void scatter_edges(const int* __restrict__ ei, const int* __restrict__ flags,
                              int* __restrict__ cursor, int* __restrict__ csr_src, int E_){
  int e = blockIdx.x * blockDim.x + threadIdx.x;
  if (e >= E_) return;
  int is64 = flags[0];
  int src, dst;
  edge_nodes(ei, E_, is64, e, src, dst);
  int pos = atomAddI(&cursor[dst], 1);
  csr_src[pos] = src;
}

// ---------------- fused per-dst gather: softmax + weighted sum + bias ----------------
// one wave per dst node; 2 edges in flight (half-wave each); lane k of 32 owns
// feature k. EXACT round-4 version (passed) — the r5/r6 preload+shfl-broadcast
// variant produced sporadic wrong src indices (~0.04 absmax), do not reintroduce.
__global__ void gat_gather(const int* __restrict__ row, const int* __restrict__ csr_src,
                           const float* __restrict__ xl, const float* __restrict__ xr,
                           const void* __restrict__ att, const void* __restrict__ bias,
                           const int* __restrict__ flags,
                           float* __restrict__ outp, int N_, int do_relu)
{
  int n = blockIdx.x * (blockDim.x >> 6) + (threadIdx.x >> 6);
  if (n >= N_) return;
  int lane = threadIdx.x & 63;
  int half = lane >> 5, k = lane & 31;
  int f32 = flags[1];
  float attk = ldf(att, f32, k);
  float xrk = xr[(size_t)n*D_HID + k];
  int rs = row[n], re = row[n+1];
  float acc = 0.f, ssum = 0.f;
  for (int i = rs + half; i < re; i += 2){
    int src = csr_src[i];
    float xlv = xl[(size_t)src*D_HID + k];
    float h = xlv + xrk;
    h = h > 0.f ? h : NEG*h;
    float p = h * attk;
    p += __shfl_xor(p, 16, 32);
    p += __shfl_xor(p,  8, 32);
    p += __shfl_xor(p,  4, 32);
    p += __shfl_xor(p,  2, 32);
    p += __shfl_xor(p,  1, 32);
    p = fminf(p, 60.f);          // safety clamp; real logits |.| <~ 15
    float ev = __expf(p);
    ssum += ev;
    acc = fmaf(ev, xlv, acc);
  }
  // combine the two half-wave partial sums (lane^32 has same k)
  acc  += __shfl_xor(acc, 32, 64);
  ssum += __shfl_xor(ssum, 32, 64);
  if (half == 0){
    float v = acc / (ssum + 1e-16f) + ldf(bias, f32, k);
    if (do_relu) v = v > 0.f ? v : 0.f;
    outp[(size_t)n*D_HID + k] = v;
  }
}

extern "C" void kernel_launch(void* const* d_in, const int* in_sizes, int n_in,
                              void* d_out, int out_size, void* d_ws, size_t ws_size,
                              hipStream_t stream)
{
  const void* x   = d_in[0];
  const int*  ei  = (const int*)d_in[1];
  const void* W1l = d_in[2];
  const void* W1r = d_in[3];
  const void* att1= d_in[4];
  const void* b1  = d_in[5];
  const void* W2l = d_in[6];
  const void* W2r = d_in[7];
  const void* att2= d_in[8];
  const void* b2  = d_in[9];
  float* out = (float*)d_out;

  int N_ = in_sizes[0] / D_IN;
  int E_ = in_sizes[1] / 2;

  char* ws = (char*)d_ws;
  size_t off = 0;
  auto carve = [&](size_t bytes) -> char* {
    char* p = ws + off;
    off += (bytes + 255) & ~(size_t)255;
    return p;
  };
  float* xl     = (float*)carve((size_t)N_ * D_HID * 4);
  float* xr     = (float*)carve((size_t)N_ * D_HID * 4);
  float* h      = (float*)carve((size_t)N_ * D_HID * 4);
  int*   csr_src= (int*)  carve((size_t)E_ * 4);
  int*   row    = (int*)  carve((size_t)(N_ + 1) * 4);
  int*   deg    = (int*)  carve((size_t)N_ * 4);   // doubles as cursor after scan
  int*   bsum   = (int*)  carve(4096);
  int*   flags  = (int*)  carve(256);
  int*   cursor = deg;

  const int tpb = 256;
  int gN  = (N_ + tpb - 1) / tpb;           // node grid (1 thread/node)
  int gE  = (E_ + tpb - 1) / tpb;           // edge grid
  int NB  = (N_ + 255) / 256;               // scan chunks (<=512 for N<=131072)
  int gW  = (N_ + 3) / 4;                   // wave-per-node grid (4 waves/block)

  detect_flags<<<1, 256, 0, stream>>>(ei, (const u16*)x, flags);

  // ---- CSR build (shared by both layers) ----
  hipMemsetAsync(deg, 0, (size_t)N_ * 4, stream);
  count_deg<<<gE, tpb, 0, stream>>>(ei, flags, deg, E_);
  scan_partial<<<NB, 256, 0, stream>>>(deg, bsum, N_);
  scan_bsum<<<1, 512, 0, stream>>>(bsum, NB);
  scan_write<<<NB, 256, 0, stream>>>(deg, bsum, row, cursor, N_, E_);
  scatter_edges<<<gE, tpb, 0, stream>>>(ei, flags, cursor, csr_src, E_);

  // ---- layer 1 ----
  node_gemm<D_IN><<<gN, tpb, 0, stream>>>(x, W1l, W1r, flags, 0, xl, xr, N_);
  gat_gather<<<gW, tpb, 0, stream>>>(row, csr_src, xl, xr, att1, b1, flags, h, N_, 1);

  // ---- layer 2 ----
  node_gemm<D_HID><<<gN, tpb, 0, stream>>>(h, W2l, W2r, flags, 1, xl, xr, N_);
  gat_gather<<<gW, tpb, 0, stream>>>(row, csr_src, xl, xr, att2, b2, flags, out, N_, 0);
}